// Round 9
// baseline (311.970 us; speedup 1.0000x reference)
//
#include <hip/hip_runtime.h>

// GraphSAGE fused forward — live path only (neighbors_2/W1 are dead code).
// r7 instrumentation: per-rep ~28us, VALUBusy 20.6%, Occ 21% (76KB LDS cap),
// 5.24M LDS bank-conflict cycles; LDS-volume+occupancy bound.
// This round: 8-seed acc blocking (per-lane W LDS traffic /4), LDS overlays
// (44KB -> 4 waves/SIMD), 1-barrier-per-panel pipeline, all-8-wave output.
//
//   d_in[0] nodes        int32 [4096]
//   d_in[1] neighbors_1  int32 [4096,16]
//   d_in[2] neighbors_2  (UNUSED)
//   d_in[3] node_features f32  [100000,128]
//   d_in[4] W1           (UNUSED)
//   d_in[5] W2           f32   [128,256]
//   d_in[6] Wo           f32   [64,128]
// out: softmax(relu(cat[feat, mean_nbr] @ W2^T) @ Wo^T)  f32 [4096,64]

constexpr int D = 128;
constexpr int H = 128;
constexpr int O = 64;
constexpr int S = 16;
constexpr int NB = 4096;
constexpr int SPB = 8;      // seeds/block -> 512 blocks
constexpr int T   = 512;    // 8 waves/block
constexpr int KP  = 32;     // W2 k-panel width (8 panels)

__global__ __launch_bounds__(T, 4) void sage_fused(
    const int* __restrict__ nodes,
    const int* __restrict__ neigh,
    const float* __restrict__ nf,
    const float* __restrict__ W2,
    const float* __restrict__ Wo,
    float* __restrict__ out)
{
    // LDS overlays: phase1 {w2l dbuf, catl}; phase2 {wol, part}; hl separate.
    __shared__ __align__(16) char smA[2 * H * KP * 4];   // 32 KB
    __shared__ __align__(16) char smB[SPB * 2 * D * 4];  //  8 KB
    __shared__ float hl[SPB][H];                         //  4 KB  (44 KB total)

    float (&w2l)[2][H][KP]    = *reinterpret_cast<float(*)[2][H][KP]>(smA);
    float (&wol)[O][D]        = *reinterpret_cast<float(*)[O][D]>(smA);
    float (&catl)[SPB][2 * D] = *reinterpret_cast<float(*)[SPB][2 * D]>(smB);
    float (&part)[2][SPB][H]  = *reinterpret_cast<float(*)[2][SPB][H]>(smB);

    const int t  = threadIdx.x;
    const int s0 = blockIdx.x * SPB;

    // ---- early global loads: W2 panel 0, Wo (held in regs until late) ----
    float4 pv[2];
    #pragma unroll
    for (int i = 0; i < 2; ++i) {
        const int idx = t + i * T, row = idx >> 3, c4 = idx & 7;
        pv[i] = *reinterpret_cast<const float4*>(W2 + (size_t)row * (2 * D) + c4 * 4);
    }
    float4 wv[4];
    #pragma unroll
    for (int i = 0; i < 4; ++i)
        wv[i] = reinterpret_cast<const float4*>(Wo)[t + i * T];

    // ---- gather: wave w (t>>6) owns seed s0+w; lanes 2x32 neighbor halves ----
    {
        const int w    = t >> 6;
        const int lane = t & 63;
        const int d4   = lane & 31;
        const int sub  = lane >> 5;
        const float4* nf4 = reinterpret_cast<const float4*>(nf);

        const int4* nbp = reinterpret_cast<const int4*>(
            neigh + (size_t)(s0 + w) * S + sub * 8);
        const int4 a = nbp[0], b = nbp[1];
        const int ids[8] = {a.x, a.y, a.z, a.w, b.x, b.y, b.z, b.w};

        const float4 org = nf4[(size_t)nodes[s0 + w] * (D / 4) + d4];
        float4 sum = make_float4(0.f, 0.f, 0.f, 0.f);
        #pragma unroll
        for (int s = 0; s < 8; ++s) {
            const float4 v = nf4[(size_t)ids[s] * (D / 4) + d4];
            sum.x += v.x; sum.y += v.y; sum.z += v.z; sum.w += v.w;
        }
        float4 tot;
        tot.x = sum.x + __shfl_xor(sum.x, 32);
        tot.y = sum.y + __shfl_xor(sum.y, 32);
        tot.z = sum.z + __shfl_xor(sum.z, 32);
        tot.w = sum.w + __shfl_xor(sum.w, 32);
        if (sub == 0) {
            *reinterpret_cast<float4*>(&catl[w][4 * d4]) = org;
        } else {
            *reinterpret_cast<float4*>(&catl[w][D + 4 * d4]) =
                make_float4(tot.x * 0.0625f, tot.y * 0.0625f,
                            tot.z * 0.0625f, tot.w * 0.0625f);
        }
    }

    // ---- write panel 0, prefetch panel 1 ----
    #pragma unroll
    for (int i = 0; i < 2; ++i) {
        const int idx = t + i * T, row = idx >> 3, c4 = idx & 7;
        *reinterpret_cast<float4*>(&w2l[0][row][(c4 ^ (row & 7)) << 2]) = pv[i];
    }
    #pragma unroll
    for (int i = 0; i < 2; ++i) {
        const int idx = t + i * T, row = idx >> 3, c4 = idx & 7;
        pv[i] = *reinterpret_cast<const float4*>(
            W2 + (size_t)row * (2 * D) + KP + c4 * 4);
    }

    // ---- panel loop: thread = (row j, k-half h, seed-quad sg) ----
    const int j   = t & 127;          // W2 output row
    const int h   = (t >> 7) & 1;     // k-half of panel (16 k)
    const int sg  = t >> 8;           // seed quad: seeds sg*4 .. sg*4+3
    const int swz = j & 7;
    float acc[4] = {0.f, 0.f, 0.f, 0.f};

    for (int p = 0; p < 8; ++p) {
        const int cur = p & 1;
        __syncthreads();   // panel p staged by all; prior-panel readers done
        if (p < 7) {       // write panel p+1 (opposite buffer; its readers done)
            #pragma unroll
            for (int i = 0; i < 2; ++i) {
                const int idx = t + i * T, row = idx >> 3, c4 = idx & 7;
                *reinterpret_cast<float4*>(
                    &w2l[cur ^ 1][row][(c4 ^ (row & 7)) << 2]) = pv[i];
            }
            if (p < 6) {
                #pragma unroll
                for (int i = 0; i < 2; ++i) {
                    const int idx = t + i * T, row = idx >> 3, c4 = idx & 7;
                    pv[i] = *reinterpret_cast<const float4*>(
                        W2 + (size_t)row * (2 * D) + (p + 2) * KP + c4 * 4);
                }
            }
        }
        #pragma unroll
        for (int kk = 0; kk < 4; ++kk) {
            const int k4 = h * 4 + kk;                  // panel-local k4 (0..7)
            const float4 w = *reinterpret_cast<const float4*>(
                &w2l[cur][j][(k4 ^ swz) << 2]);
            #pragma unroll
            for (int s = 0; s < 4; ++s) {
                const float4 c = *reinterpret_cast<const float4*>(
                    &catl[sg * 4 + s][p * KP + k4 * 4]);  // wave-uniform
                acc[s] = fmaf(w.x, c.x, acc[s]);
                acc[s] = fmaf(w.y, c.y, acc[s]);
                acc[s] = fmaf(w.z, c.z, acc[s]);
                acc[s] = fmaf(w.w, c.w, acc[s]);
            }
        }
    }
    __syncthreads();       // all compute(7) done: catl & w2l regions now free

    // ---- partials -> part (overlays catl); Wo -> wol (overlays w2l) ----
    #pragma unroll
    for (int s = 0; s < 4; ++s)
        part[h][sg * 4 + s][j] = acc[s];
    #pragma unroll
    for (int i = 0; i < 4; ++i) {        // wol[c][k4 ^ (c&7)] quad-swizzle
        const int idx = t + i * T, c = idx >> 5, k4 = idx & 31;
        *reinterpret_cast<float4*>(
            &wol[c][((k4 & 24) | ((k4 ^ c) & 7)) << 2]) = wv[i];
    }
    __syncthreads();

    // ---- hl = relu(part0 + part1) ----
    #pragma unroll
    for (int i2 = 0; i2 < 2; ++i2) {
        const int i = t + i2 * T;
        const int s = i >> 7, jj = i & 127;
        const float v = part[0][s][jj] + part[1][s][jj];
        hl[s][jj] = v > 0.f ? v : 0.f;
    }
    __syncthreads();

    // ---- output layer + softmax: wave g owns seed g; lane = class ----
    {
        const int c = t & 63;
        const int g = t >> 6;            // seed index 0..7
        const int cswz = c & 7;
        float a = 0.f;
        #pragma unroll
        for (int k4 = 0; k4 < 32; ++k4) {
            const float4 w = *reinterpret_cast<const float4*>(
                &wol[c][((k4 & 24) | ((k4 ^ cswz) & 7)) << 2]);
            const float4 hv = *reinterpret_cast<const float4*>(&hl[g][k4 * 4]);
            a = fmaf(w.x, hv.x, a); a = fmaf(w.y, hv.y, a);
            a = fmaf(w.z, hv.z, a); a = fmaf(w.w, hv.w, a);
        }
        float m = a;
        #pragma unroll
        for (int off = 32; off >= 1; off >>= 1)
            m = fmaxf(m, __shfl_xor(m, off));
        const float e = __expf(a - m);
        float z = e;
        #pragma unroll
        for (int off = 32; off >= 1; off >>= 1)
            z += __shfl_xor(z, off);
        out[(size_t)(s0 + g) * O + c] = e / z;
    }
}

extern "C" void kernel_launch(void* const* d_in, const int* in_sizes, int n_in,
                              void* d_out, int out_size, void* d_ws, size_t ws_size,
                              hipStream_t stream) {
    const int*   nodes         = (const int*)d_in[0];
    const int*   neighbors_1   = (const int*)d_in[1];
    const float* node_features = (const float*)d_in[3];
    const float* W2            = (const float*)d_in[5];
    const float* Wo            = (const float*)d_in[6];
    float*       out           = (float*)d_out;

    sage_fused<<<NB / SPB, T, 0, stream>>>(
        nodes, neighbors_1, node_features, W2, Wo, out);
}